// Round 8
// baseline (41.675 us; speedup 1.0000x reference)
//
#include <hip/hip_runtime.h>
#include <math.h>

#define K_TOP 16
#define D_DIM 1024
#define N_ROWS 2048                       // 32 * 64 rows

typedef float f32x4 __attribute__((ext_vector_type(4)));

// One block (256 thr) per row q. ALL 4 waves redundantly:
//   1) load logits[r]+gn[q] (f32x4, lane owns d=lane*16+j) — same 8 KB for
//      all waves, so 3 of 4 hit L1;
//   2) 16 rounds of {per-lane masked argmax -> 64-lane butterfly argmax},
//      tie-break prefers smaller index; rank-sort ascending by index;
//   3) invert the rank permutation via 16 broadcast shuffles to get the
//      wave's own 4 sorted winners;
//   4) write k-rows wave*4 .. wave*4+3 with the 1.0 merged into the
//      streaming f32x4 stores.
// No LDS, no barrier, no scatter, no cross-wave communication.
__global__ __launch_bounds__(256) void dps_topk_kernel(
    const float* __restrict__ logits,  // (64, 1024)
    const float* __restrict__ gn,      // (32, 64, 1024)
    float* __restrict__ out)           // (32, 64, 16, 1024)
{
    const int tid  = threadIdx.x;
    const int lane = tid & 63;
    const int wave = tid >> 6;
    const int q    = blockIdx.x;
    const int r    = q & 63;

    // ---- load + perturb: lane owns 16 consecutive elements (64 B) ----
    float v[16];
    {
        const f32x4* l4 = reinterpret_cast<const f32x4*>(
            logits + (size_t)r * D_DIM + lane * 16);
        const f32x4* g4 = reinterpret_cast<const f32x4*>(
            gn + (size_t)q * D_DIM + lane * 16);
        #pragma unroll
        for (int c = 0; c < 4; ++c) {
            const f32x4 a = l4[c];
            const f32x4 b = g4[c];
            v[c * 4 + 0] = a.x + b.x;
            v[c * 4 + 1] = a.y + b.y;
            v[c * 4 + 2] = a.z + b.z;
            v[c * 4 + 3] = a.w + b.w;
        }
    }

    // ---- 16 rounds of wave-wide argmax (identical in every wave) ----
    unsigned chosen = 0;   // bitmask of already-taken j's in THIS lane
    int my_sel = 0;        // lane k ends up holding round-k winner's index
    for (int round = 0; round < K_TOP; ++round) {
        float bv = -INFINITY;
        int   bi = 0x7fffffff;
        #pragma unroll
        for (int j = 0; j < 16; ++j) {
            if (!(chosen & (1u << j))) {
                // strict > keeps smaller j (= smaller index) on ties
                if (v[j] > bv) { bv = v[j]; bi = lane * 16 + j; }
            }
        }
        #pragma unroll
        for (int off = 32; off > 0; off >>= 1) {
            const float ov = __shfl_xor(bv, off);
            const int   oi = __shfl_xor(bi, off);
            if (ov > bv || (ov == bv && oi < bi)) { bv = ov; bi = oi; }
        }
        if (lane == (bi >> 4)) chosen |= 1u << (bi & 15);
        if (lane == round)     my_sel = bi;
    }

    // ---- rank among the 16 winners = ascending index order ----
    int rank = 0;
    #pragma unroll
    for (int j = 0; j < K_TOP; ++j) {
        const int other = __shfl(my_sel, j);
        rank += (other < my_sel) ? 1 : 0;
    }

    // ---- invert the permutation: s_kk = winner with rank == wave*4+kk ----
    int s0 = 0, s1 = 0, s2 = 0, s3 = 0;
    const int kbase = wave * 4;
    #pragma unroll
    for (int j = 0; j < K_TOP; ++j) {
        const int rj = __shfl(rank,   j);
        const int sj = __shfl(my_sel, j);
        if (rj == kbase + 0) s0 = sj;
        if (rj == kbase + 1) s1 = sj;
        if (rj == kbase + 2) s2 = sj;
        if (rj == kbase + 3) s3 = sj;
    }

    // ---- write own 4 k-rows with the 1.0 merged into streaming stores ----
    f32x4* o4 = reinterpret_cast<f32x4*>(out + (size_t)q * (K_TOP * D_DIM));
    const f32x4 zero = {0.f, 0.f, 0.f, 0.f};
    int sel[4];  // static-indexed via unroll below
    sel[0] = s0; sel[1] = s1; sel[2] = s2; sel[3] = s3;
    #pragma unroll
    for (int kk = 0; kk < 4; ++kk) {
        const int s  = sel[kk];
        const int sv = s >> 2;             // which f32x4 holds the 1
        f32x4 hot;
        hot.x = ((s & 3) == 0) ? 1.0f : 0.0f;
        hot.y = ((s & 3) == 1) ? 1.0f : 0.0f;
        hot.z = ((s & 3) == 2) ? 1.0f : 0.0f;
        hot.w = ((s & 3) == 3) ? 1.0f : 0.0f;
        f32x4* krow = o4 + (kbase + kk) * 256;
        #pragma unroll
        for (int c = 0; c < 4; ++c) {
            const int f4idx = c * 64 + lane;
            krow[f4idx] = (f4idx == sv) ? hot : zero;
        }
    }
}

extern "C" void kernel_launch(void* const* d_in, const int* in_sizes, int n_in,
                              void* d_out, int out_size, void* d_ws, size_t ws_size,
                              hipStream_t stream) {
    const float* logits = (const float*)d_in[0];  // (64, 1024) f32
    const float* gn     = (const float*)d_in[1];  // (32, 64, 1024) f32
    float* out          = (float*)d_out;          // (32, 64, 16, 1024) f32

    dps_topk_kernel<<<dim3(N_ROWS), dim3(256), 0, stream>>>(logits, gn, out);
}

// Round 9
// 39.950 us; speedup vs baseline: 1.0432x; 1.0432x over previous
//
#include <hip/hip_runtime.h>
#include <math.h>

#define K_TOP 16
#define D_DIM 1024
#define N_ROWS 2048                       // 32 * 64 rows

typedef float f32x4 __attribute__((ext_vector_type(4)));

// Select + scatter only (zeros are done by hipMemsetAsync before this).
// One wave per row q = blockIdx.x*4 + wave. Lane owns d = lane*16+j
// (coalesced f32x4 loads). 16 rounds of {per-lane masked argmax ->
// 64-lane butterfly argmax}, tie-break prefers smaller global index
// (matches np argsort; exact ties are measure-zero for random f32).
// Rank-sort ascending by index, then lanes 0..15 store the 16 ones.
__global__ __launch_bounds__(256) void select_scatter_kernel(
    const float* __restrict__ logits,  // (64, 1024)
    const float* __restrict__ gn,      // (32, 64, 1024)
    float* __restrict__ out)           // (32, 64, 16, 1024)
{
    const int tid  = threadIdx.x;
    const int lane = tid & 63;
    const int wave = tid >> 6;
    const int q    = blockIdx.x * 4 + wave;
    const int r    = q & 63;

    // ---- load + perturb: lane owns 16 consecutive elements (64 B) ----
    float v[16];
    {
        const f32x4* l4 = reinterpret_cast<const f32x4*>(
            logits + (size_t)r * D_DIM + lane * 16);
        const f32x4* g4 = reinterpret_cast<const f32x4*>(
            gn + (size_t)q * D_DIM + lane * 16);
        #pragma unroll
        for (int c = 0; c < 4; ++c) {
            const f32x4 a = l4[c];
            const f32x4 b = g4[c];
            v[c * 4 + 0] = a.x + b.x;
            v[c * 4 + 1] = a.y + b.y;
            v[c * 4 + 2] = a.z + b.z;
            v[c * 4 + 3] = a.w + b.w;
        }
    }

    // ---- 16 rounds of wave-wide argmax ----
    unsigned chosen = 0;   // bitmask of already-taken j's in THIS lane
    int my_sel = 0;        // lane k ends up holding round-k winner's index
    for (int round = 0; round < K_TOP; ++round) {
        float bv = -INFINITY;
        int   bi = 0x7fffffff;
        #pragma unroll
        for (int j = 0; j < 16; ++j) {
            if (!(chosen & (1u << j))) {
                // strict > keeps smaller j (= smaller index) on ties
                if (v[j] > bv) { bv = v[j]; bi = lane * 16 + j; }
            }
        }
        #pragma unroll
        for (int off = 32; off > 0; off >>= 1) {
            const float ov = __shfl_xor(bv, off);
            const int   oi = __shfl_xor(bi, off);
            if (ov > bv || (ov == bv && oi < bi)) { bv = ov; bi = oi; }
        }
        if (lane == (bi >> 4)) chosen |= 1u << (bi & 15);  // owner retires it
        if (lane == round)     my_sel = bi;
    }

    // ---- rank among the 16 winners = ascending index order ----
    int rank = 0;
    #pragma unroll
    for (int j = 0; j < K_TOP; ++j) {
        const int other = __shfl(my_sel, j);
        rank += (other < my_sel) ? 1 : 0;
    }

    // ---- scatter the 16 ones: out[q][rank][my_sel] = 1 ----
    if (lane < K_TOP) {
        out[(size_t)q * (K_TOP * D_DIM) + (size_t)rank * D_DIM + my_sel] = 1.0f;
    }
}

extern "C" void kernel_launch(void* const* d_in, const int* in_sizes, int n_in,
                              void* d_out, int out_size, void* d_ws, size_t ws_size,
                              hipStream_t stream) {
    const float* logits = (const float*)d_in[0];  // (64, 1024) f32
    const float* gn     = (const float*)d_in[1];  // (32, 64, 1024) f32
    float* out          = (float*)d_out;          // (32, 64, 16, 1024) f32

    // Zero the whole output via the runtime's tuned fill kernel
    // (graph-capturable; measured 6.4-6.9 TB/s on this chip).
    hipMemsetAsync(d_out, 0, (size_t)out_size * sizeof(float), stream);

    // Then scatter the 16 ones per row.
    select_scatter_kernel<<<dim3(N_ROWS / 4), dim3(256), 0, stream>>>(
        logits, gn, out);
}